// Round 1
// baseline (403.297 us; speedup 1.0000x reference)
//
#include <hip/hip_runtime.h>
#include <hip/hip_bf16.h>

typedef __attribute__((ext_vector_type(4))) float f32x4;
typedef __attribute__((ext_vector_type(8))) short short8;
typedef unsigned short u16;

typedef const __attribute__((address_space(1))) void* gas_ptr;
typedef __attribute__((address_space(3))) void* las_ptr;

#define HW 9216
#define NROW 2048
#define CCH 128

__device__ __forceinline__ u16 f2bf(float x) {
  unsigned u = __float_as_uint(x);
  u += 0x7fffu + ((u >> 16) & 1u);   // round-to-nearest-even
  return (u16)(u >> 16);
}

__device__ __forceinline__ void async16(const void* g, void* l) {
  __builtin_amdgcn_global_load_lds((gas_ptr)g, (las_ptr)l, 16, 0, 0);
}

// ---------------- kernel 0: convert weights fp32 -> bf16 ----------------
__global__ __launch_bounds__(256) void wcvt_kernel(
    const float* __restrict__ wq, const float* __restrict__ wk, const float* __restrict__ wv,
    u16* __restrict__ oq, u16* __restrict__ ok, u16* __restrict__ ov) {
  int i = blockIdx.x * 256 + threadIdx.x;
  if (i < CCH * CCH) {
    oq[i] = f2bf(wq[i]);
    ok[i] = f2bf(wk[i]);
    ov[i] = f2bf(wv[i]);
  }
}

// ---------------- kernel 1: fused projections q,k,v ----------------
// q[b*128+o][hw] = sum_c Wq[o][c] f[b][c][hw]   (row-major bf16 [2048][9216])
// k likewise from e_in; v written TRANSPOSED: vt[hw][b*128+o]  ([9216][2048])
__global__ __launch_bounds__(256) void proj_kernel(
    const float* __restrict__ f_in, const float* __restrict__ e_in,
    const u16* __restrict__ Wq, const u16* __restrict__ Wk, const u16* __restrict__ Wv,
    u16* __restrict__ q, u16* __restrict__ kmat, u16* __restrict__ vt) {
  __shared__ __align__(16) u16 Fs[64][128];   // F^T tile: [hw][c], c-blocks XOR-swizzled
  __shared__ __align__(16) u16 Es[64][128];
  const int tid = threadIdx.x;
  const int lane = tid & 63;
  const int w = tid >> 6;
  const int b = blockIdx.y;
  const int hw0 = blockIdx.x * 64;
  const size_t base = (size_t)b * CCH * HW + hw0;

  // stage: wave w loads c-blocks {w, w+4, w+8, w+12}, lane = hw (coalesced over lanes)
  #pragma unroll
  for (int it = 0; it < 4; ++it) {
    int g = w + 4 * it;                       // 8-channel block index 0..15
    const float* fp = f_in + base + (size_t)(g * 8) * HW + lane;
    const float* ep = e_in + base + (size_t)(g * 8) * HW + lane;
    short8 fv, ev;
    #pragma unroll
    for (int j = 0; j < 8; ++j) {
      fv[j] = (short)f2bf(fp[(size_t)j * HW]);
      ev[j] = (short)f2bf(ep[(size_t)j * HW]);
    }
    int gs = (g & 8) | ((g & 7) ^ (lane & 7));   // bank-conflict swizzle (involution)
    *(short8*)&Fs[lane][gs * 8] = fv;
    *(short8*)&Es[lane][gs * 8] = ev;
  }
  __syncthreads();

  const int wr = w >> 1, wc = w & 1;          // wave tile: 64 o x 32 hw
  const int lr = lane & 15, lg = lane >> 4;
  f32x4 accq[4][2] = {};
  f32x4 acck[4][2] = {};
  f32x4 accv[4][2] = {};

  #pragma unroll
  for (int kk = 0; kk < 4; ++kk) {
    short8 bF[2], bE[2];
    #pragma unroll
    for (int n = 0; n < 2; ++n) {
      int col = wc * 32 + n * 16 + lr;
      int gidx = kk * 4 + lg;
      int gsw = (gidx & 8) | ((gidx & 7) ^ (col & 7));
      bF[n] = *(const short8*)&Fs[col][gsw * 8];
      bE[n] = *(const short8*)&Es[col][gsw * 8];
    }
    #pragma unroll
    for (int m = 0; m < 4; ++m) {
      int o = wr * 64 + m * 16 + lr;
      int woff = o * CCH + kk * 32 + lg * 8;
      short8 aQ = *(const short8*)(Wq + woff);
      short8 aK = *(const short8*)(Wk + woff);
      short8 aV = *(const short8*)(Wv + woff);
      #pragma unroll
      for (int n = 0; n < 2; ++n) {
        accq[m][n] = __builtin_amdgcn_mfma_f32_16x16x32_bf16(aQ, bF[n], accq[m][n], 0, 0, 0);
        acck[m][n] = __builtin_amdgcn_mfma_f32_16x16x32_bf16(aK, bE[n], acck[m][n], 0, 0, 0);
        accv[m][n] = __builtin_amdgcn_mfma_f32_16x16x32_bf16(aV, bF[n], accv[m][n], 0, 0, 0);
      }
    }
  }

  #pragma unroll
  for (int m = 0; m < 4; ++m) {
    #pragma unroll
    for (int n = 0; n < 2; ++n) {
      int o0 = wr * 64 + m * 16 + 4 * lg;
      int col = hw0 + wc * 32 + n * 16 + lr;
      int row0 = b * CCH + o0;
      #pragma unroll
      for (int i = 0; i < 4; ++i) {
        q[(size_t)(row0 + i) * HW + col] = f2bf(accq[m][n][i]);
        kmat[(size_t)(row0 + i) * HW + col] = f2bf(acck[m][n][i]);
      }
      ushort4 pv;
      pv.x = f2bf(accv[m][n][0]);
      pv.y = f2bf(accv[m][n][1]);
      pv.z = f2bf(accv[m][n][2]);
      pv.w = f2bf(accv[m][n][3]);
      *(ushort4*)&vt[(size_t)col * NROW + row0] = pv;   // 4 consecutive rows -> 8B store
    }
  }
}

// ---------------- GEMM: C[M,N] (+= resid) = A[M,K] * BT[N,K]^T, bf16 in fp32 out ----
// m97 structure: 128x128 tile, BK=32, 4 waves (2x2), global_load_lds width 16.
template <int EPI>   // 0: plain fp32 write (split-K partial), 1: += resid (fused residual)
__global__ __launch_bounds__(256) void gemm_bt(
    const u16* __restrict__ A, const u16* __restrict__ BT,
    int lda, int N, int nk, int kstride_z, long long cstride_z,
    float* __restrict__ C, const float* __restrict__ resid) {
  __shared__ __align__(16) u16 As[128 * 32];
  __shared__ __align__(16) u16 Bs[128 * 32];
  const int tid = threadIdx.x;
  const int lane = tid & 63;
  const int w = tid >> 6;
  const int wr = w >> 1, wc = w & 1;
  const int lr = lane & 15, lg = lane >> 4;
  const int bm = blockIdx.y * 128;
  const int bn = blockIdx.x * 128;
  const int kz = blockIdx.z;

  const u16* Ag = A + (size_t)kz * kstride_z;
  const u16* Bg = BT + (size_t)kz * kstride_z;
  float* Cg = C + (size_t)kz * cstride_z;

  const int e0 = tid * 8;            // element index in 128x32 tile
  const int r0 = e0 >> 5;
  const int k0 = e0 & 31;
  const u16* gA0 = Ag + (size_t)(bm + r0) * lda + k0;
  const u16* gA1 = gA0 + (size_t)64 * lda;
  const u16* gB0 = Bg + (size_t)(bn + r0) * lda + k0;
  const u16* gB1 = gB0 + (size_t)64 * lda;
  u16* lA0 = &As[e0];
  u16* lA1 = &As[e0 + 2048];
  u16* lB0 = &Bs[e0];
  u16* lB1 = &Bs[e0 + 2048];

  f32x4 acc[4][4] = {};

  for (int kt = 0; kt < nk; ++kt) {
    async16(gA0, lA0);
    async16(gA1, lA1);
    async16(gB0, lB0);
    async16(gB1, lB1);
    gA0 += 32; gA1 += 32; gB0 += 32; gB1 += 32;
    __syncthreads();                  // drains vmcnt -> staged data visible
    short8 a[4], bb[4];
    #pragma unroll
    for (int m = 0; m < 4; ++m)
      a[m] = *(const short8*)&As[(wr * 64 + m * 16 + lr) * 32 + lg * 8];
    #pragma unroll
    for (int n = 0; n < 4; ++n)
      bb[n] = *(const short8*)&Bs[(wc * 64 + n * 16 + lr) * 32 + lg * 8];
    #pragma unroll
    for (int m = 0; m < 4; ++m)
      #pragma unroll
      for (int n = 0; n < 4; ++n)
        acc[m][n] = __builtin_amdgcn_mfma_f32_16x16x32_bf16(a[m], bb[n], acc[m][n], 0, 0, 0);
    __syncthreads();                  // all waves done reading before next stage
  }

  #pragma unroll
  for (int m = 0; m < 4; ++m) {
    #pragma unroll
    for (int n = 0; n < 4; ++n) {
      int row0 = bm + wr * 64 + m * 16 + 4 * lg;
      int col = bn + wc * 64 + n * 16 + lr;
      #pragma unroll
      for (int i = 0; i < 4; ++i) {
        size_t idx = (size_t)(row0 + i) * N + col;
        float v = acc[m][n][i];
        if (EPI == 1) v += resid[idx];
        Cg[idx] = v;
      }
    }
  }
}

// ---------------- softmax over rows, summing 3 split-K partials, emit bf16 P ----
__global__ __launch_bounds__(256) void softmax3_kernel(
    const float* __restrict__ sim, u16* __restrict__ P) {
  const int row = blockIdx.x;
  const int t = threadIdx.x;
  const int lane = t & 63, w = t >> 6;
  const float* r0 = sim + (size_t)row * NROW + t * 8;
  const float* r1 = r0 + 4194304;    // partial 1 (2048*2048)
  const float* r2 = r1 + 4194304;    // partial 2
  float x[8];
  #pragma unroll
  for (int j = 0; j < 8; ++j) x[j] = r0[j] + r1[j] + r2[j];

  float m = x[0];
  #pragma unroll
  for (int j = 1; j < 8; ++j) m = fmaxf(m, x[j]);
  #pragma unroll
  for (int o = 1; o < 64; o <<= 1) m = fmaxf(m, __shfl_xor(m, o));
  __shared__ float redm[4], reds[4];
  if (lane == 0) redm[w] = m;
  __syncthreads();
  m = fmaxf(fmaxf(redm[0], redm[1]), fmaxf(redm[2], redm[3]));

  float e[8];
  float s = 0.f;
  #pragma unroll
  for (int j = 0; j < 8; ++j) { e[j] = __expf(x[j] - m); s += e[j]; }
  #pragma unroll
  for (int o = 1; o < 64; o <<= 1) s += __shfl_xor(s, o);
  if (lane == 0) reds[w] = s;
  __syncthreads();
  s = reds[0] + reds[1] + reds[2] + reds[3];
  float inv = 1.f / s;

  short8 pv;
  #pragma unroll
  for (int j = 0; j < 8; ++j) pv[j] = (short)f2bf(e[j] * inv);
  *(short8*)(P + (size_t)row * NROW + t * 8) = pv;
}

// ---------------- launch ----------------
extern "C" void kernel_launch(void* const* d_in, const int* in_sizes, int n_in,
                              void* d_out, int out_size, void* d_ws, size_t ws_size,
                              hipStream_t stream) {
  const float* f_in = (const float*)d_in[0];
  const float* e_in = (const float*)d_in[1];
  const float* Wq = (const float*)d_in[2];
  const float* Wk = (const float*)d_in[3];
  const float* Wv = (const float*)d_in[4];
  float* out = (float*)d_out;
  char* ws = (char*)d_ws;

  // ws layout (bytes): total ~172.1 MB
  u16* wq_bf = (u16*)(ws + 0);
  u16* wk_bf = (u16*)(ws + 32768);
  u16* wv_bf = (u16*)(ws + 65536);
  u16* q    = (u16*)(ws + 98304);                       // 2048x9216 bf16
  u16* kmat = (u16*)(ws + 98304 + 37748736ull);         // 2048x9216 bf16
  u16* vt   = (u16*)(ws + 98304 + 2 * 37748736ull);     // 9216x2048 bf16 (V^T)
  float* sim = (float*)(ws + 98304 + 3 * 37748736ull);  // 3 x 2048x2048 fp32 partials
  u16* P    = (u16*)(ws + 98304 + 3 * 37748736ull + 3 * 16777216ull);  // 2048x2048 bf16

  wcvt_kernel<<<64, 256, 0, stream>>>(Wq, Wk, Wv, wq_bf, wk_bf, wv_bf);
  proj_kernel<<<dim3(144, 16), 256, 0, stream>>>(f_in, e_in, wq_bf, wk_bf, wv_bf, q, kmat, vt);
  // sim = q * k^T, split-K=3 (K=9216 -> 3x3072), 768 blocks
  gemm_bt<0><<<dim3(16, 16, 3), 256, 0, stream>>>(q, kmat, HW, NROW, 96, 3072, 4194304LL, sim, nullptr);
  softmax3_kernel<<<2048, 256, 0, stream>>>(sim, P);
  // out = P * v + f_in  (BT = v^T rows are hw), 72x16 = 1152 blocks
  gemm_bt<1><<<dim3(72, 16, 1), 256, 0, stream>>>(P, vt, NROW, HW, 64, 0, 0LL, out, f_in);
}

// Round 2
// 359.009 us; speedup vs baseline: 1.1234x; 1.1234x over previous
//
#include <hip/hip_runtime.h>
#include <hip/hip_bf16.h>

typedef __attribute__((ext_vector_type(4))) float f32x4;
typedef __attribute__((ext_vector_type(8))) short short8;
typedef unsigned short u16;

typedef const __attribute__((address_space(1))) void* gas_ptr;
typedef __attribute__((address_space(3))) void* las_ptr;

#define HW 9216
#define NROW 2048
#define CCH 128

__device__ __forceinline__ u16 f2bf(float x) {
  unsigned u = __float_as_uint(x);
  u += 0x7fffu + ((u >> 16) & 1u);   // round-to-nearest-even
  return (u16)(u >> 16);
}

__device__ __forceinline__ void async16(const void* g, void* l) {
  __builtin_amdgcn_global_load_lds((gas_ptr)g, (las_ptr)l, 16, 0, 0);
}

// ---------------- kernel 0: convert weights fp32 -> bf16 ----------------
__global__ __launch_bounds__(256) void wcvt_kernel(
    const float* __restrict__ wq, const float* __restrict__ wk, const float* __restrict__ wv,
    u16* __restrict__ oq, u16* __restrict__ ok, u16* __restrict__ ov) {
  int i = blockIdx.x * 256 + threadIdx.x;
  if (i < CCH * CCH) {
    oq[i] = f2bf(wq[i]);
    ok[i] = f2bf(wk[i]);
    ov[i] = f2bf(wv[i]);
  }
}

// ---------------- kernel 1: fused projections q,k,v (unchanged, passed r1) ----
__global__ __launch_bounds__(256) void proj_kernel(
    const float* __restrict__ f_in, const float* __restrict__ e_in,
    const u16* __restrict__ Wq, const u16* __restrict__ Wk, const u16* __restrict__ Wv,
    u16* __restrict__ q, u16* __restrict__ kmat, u16* __restrict__ vt) {
  __shared__ __align__(16) u16 Fs[64][128];
  __shared__ __align__(16) u16 Es[64][128];
  const int tid = threadIdx.x;
  const int lane = tid & 63;
  const int w = tid >> 6;
  const int b = blockIdx.y;
  const int hw0 = blockIdx.x * 64;
  const size_t base = (size_t)b * CCH * HW + hw0;

  #pragma unroll
  for (int it = 0; it < 4; ++it) {
    int g = w + 4 * it;
    const float* fp = f_in + base + (size_t)(g * 8) * HW + lane;
    const float* ep = e_in + base + (size_t)(g * 8) * HW + lane;
    short8 fv, ev;
    #pragma unroll
    for (int j = 0; j < 8; ++j) {
      fv[j] = (short)f2bf(fp[(size_t)j * HW]);
      ev[j] = (short)f2bf(ep[(size_t)j * HW]);
    }
    int gs = (g & 8) | ((g & 7) ^ (lane & 7));
    *(short8*)&Fs[lane][gs * 8] = fv;
    *(short8*)&Es[lane][gs * 8] = ev;
  }
  __syncthreads();

  const int wr = w >> 1, wc = w & 1;
  const int lr = lane & 15, lg = lane >> 4;
  f32x4 accq[4][2] = {};
  f32x4 acck[4][2] = {};
  f32x4 accv[4][2] = {};

  #pragma unroll
  for (int kk = 0; kk < 4; ++kk) {
    short8 bF[2], bE[2];
    #pragma unroll
    for (int n = 0; n < 2; ++n) {
      int col = wc * 32 + n * 16 + lr;
      int gidx = kk * 4 + lg;
      int gsw = (gidx & 8) | ((gidx & 7) ^ (col & 7));
      bF[n] = *(const short8*)&Fs[col][gsw * 8];
      bE[n] = *(const short8*)&Es[col][gsw * 8];
    }
    #pragma unroll
    for (int m = 0; m < 4; ++m) {
      int o = wr * 64 + m * 16 + lr;
      int woff = o * CCH + kk * 32 + lg * 8;
      short8 aQ = *(const short8*)(Wq + woff);
      short8 aK = *(const short8*)(Wk + woff);
      short8 aV = *(const short8*)(Wv + woff);
      #pragma unroll
      for (int n = 0; n < 2; ++n) {
        accq[m][n] = __builtin_amdgcn_mfma_f32_16x16x32_bf16(aQ, bF[n], accq[m][n], 0, 0, 0);
        acck[m][n] = __builtin_amdgcn_mfma_f32_16x16x32_bf16(aK, bE[n], acck[m][n], 0, 0, 0);
        accv[m][n] = __builtin_amdgcn_mfma_f32_16x16x32_bf16(aV, bF[n], accv[m][n], 0, 0, 0);
      }
    }
  }

  #pragma unroll
  for (int m = 0; m < 4; ++m) {
    #pragma unroll
    for (int n = 0; n < 2; ++n) {
      int o0 = wr * 64 + m * 16 + 4 * lg;
      int col = hw0 + wc * 32 + n * 16 + lr;
      int row0 = b * CCH + o0;
      #pragma unroll
      for (int i = 0; i < 4; ++i) {
        q[(size_t)(row0 + i) * HW + col] = f2bf(accq[m][n][i]);
        kmat[(size_t)(row0 + i) * HW + col] = f2bf(acck[m][n][i]);
      }
      ushort4 pv;
      pv.x = f2bf(accv[m][n][0]);
      pv.y = f2bf(accv[m][n][1]);
      pv.z = f2bf(accv[m][n][2]);
      pv.w = f2bf(accv[m][n][3]);
      *(ushort4*)&vt[(size_t)col * NROW + row0] = pv;
    }
  }
}

// ---------------- 256x256-tile deep-pipelined GEMM (T2+T3+T4+T5) ----------------
// C[M,N](+resid) = A[M,K] * BT[N,K]^T. BK=32, 8 waves (2x4), wave tile 128x64.
// LDS: 4-deep ring of (A 256x32 + B 256x32) bf16 = 4*16KB*2 = 128 KiB.
// Stage 3 tiles ahead via global_load_lds (4 instr/tile/wave); counted vmcnt(8)
// before a barrier guarantees tile t+1 landed for ALL waves before it is read.
// LDS XOR-swizzle col ^= ((row>>1)&3)<<3 applied on the pre-swizzled global
// source (linear LDS dest) and on the ds_read address (both-sides, rule 21).
#define STG_A(kt) do { int _b = ((kt) & 3) * 16384; size_t _ko = (size_t)(kt) * 32; \
  async16(gA0 + _ko, lA0 + _b); async16(gA1 + _ko, lA1 + _b); } while (0)
#define STG_B(kt) do { int _b = ((kt) & 3) * 16384; size_t _ko = (size_t)(kt) * 32; \
  async16(gB0 + _ko, lB0 + _b); async16(gB1 + _ko, lB1 + _b); } while (0)

template <int EPI>   // 0: plain fp32 write (split-K partial), 1: += resid
__global__ __launch_bounds__(512, 1) void gemm8(
    const u16* __restrict__ A, const u16* __restrict__ BT,
    int lda, int N, int NT, int nbx, int bps, int kstride, long long cstride_z,
    float* __restrict__ C, const float* __restrict__ resid) {
  __shared__ __align__(16) u16 smem[65536];   // 128 KiB
  const int tid = threadIdx.x;
  const int lane = tid & 63;
  const int wid = tid >> 6;
  const int wm = wid >> 2, wn = wid & 3;
  const int lr = lane & 15, lg = lane >> 4;

  // XCD-aware bijective swizzle (all grids are multiples of 8)
  const int nwg = gridDim.x;
  const int lin = blockIdx.x;
  const int swz = (lin & 7) * (nwg >> 3) + (lin >> 3);
  const int kz = swz / bps;
  const int rem = swz - kz * bps;
  const int by = rem / nbx;
  const int bx = rem - by * nbx;
  const int bm = by * 256, bn = bx * 256;

  const u16* Ag = A + (size_t)kz * kstride;
  const u16* Bg = BT + (size_t)kz * kstride;
  float* Cg = C + (size_t)kz * cstride_z;

  // staging addresses: thread covers 16B chunk; source col pre-swizzled
  const int srow = tid >> 2;                                    // 0..127
  const int scol = ((tid & 3) * 8) ^ (((srow >> 1) & 3) << 3);
  const u16* gA0 = Ag + (size_t)(bm + srow) * lda + scol;
  const u16* gA1 = gA0 + (size_t)128 * lda;
  const u16* gB0 = Bg + (size_t)(bn + srow) * lda + scol;
  const u16* gB1 = gB0 + (size_t)128 * lda;
  u16* lA0 = smem + tid * 8;       // linear dests (+ buf*16384)
  u16* lA1 = lA0 + 4096;
  u16* lB0 = lA0 + 8192;
  u16* lB1 = lA0 + 12288;

  // fragment read offsets (swizzled on read)
  const int fscol = (lg * 8) ^ (((lr >> 1) & 3) << 3);
  const int aoff = (wm * 128 + lr) * 32 + fscol;          // + fm*512 + buf*16384
  const int boff = 8192 + (wn * 64 + lr) * 32 + fscol;    // + fn*512

  f32x4 acc[8][4] = {};

  // prologue: stage tiles 0,1,2 (12 loads) -> tile 0 landed after vmcnt(8)
  STG_A(0); STG_B(0); STG_A(1); STG_B(1); STG_A(2); STG_B(2);
  asm volatile("s_waitcnt vmcnt(8)" ::: "memory");
  asm volatile("s_barrier" ::: "memory");

  for (int t = 0; t < NT; ++t) {
    const int bb = (t & 3) * 16384;
    short8 af[4], bf[4];
    // ---- phase 1: quadrant fm 0-3 x fn 0-3 ----
    if (t + 3 < NT) STG_A(t + 3);            // into buf (t-1)&3, freed last iter
    #pragma unroll
    for (int m = 0; m < 4; ++m) af[m] = *(const short8*)(smem + bb + aoff + m * 512);
    #pragma unroll
    for (int n = 0; n < 4; ++n) bf[n] = *(const short8*)(smem + bb + boff + n * 512);
    asm volatile("s_barrier" ::: "memory");
    __builtin_amdgcn_s_setprio(1);
    #pragma unroll
    for (int n = 0; n < 4; ++n)
      #pragma unroll
      for (int m = 0; m < 4; ++m)
        acc[m][n] = __builtin_amdgcn_mfma_f32_16x16x32_bf16(af[m], bf[n], acc[m][n], 0, 0, 0);
    __builtin_amdgcn_s_setprio(0);
    asm volatile("s_barrier" ::: "memory");
    // ---- phase 2: quadrant fm 4-7 x fn 0-3 ----
    if (t + 3 < NT) STG_B(t + 3);
    #pragma unroll
    for (int m = 0; m < 4; ++m) af[m] = *(const short8*)(smem + bb + aoff + (m + 4) * 512);
    // counted wait: guarantee tile t+1 landed (4 instr/tile FIFO), never 0 in steady state
    if (t + 3 < NT)      asm volatile("s_waitcnt vmcnt(8)" ::: "memory");
    else if (t + 2 < NT) asm volatile("s_waitcnt vmcnt(4)" ::: "memory");
    else if (t + 1 < NT) asm volatile("s_waitcnt vmcnt(0)" ::: "memory");
    asm volatile("s_barrier" ::: "memory");
    __builtin_amdgcn_s_setprio(1);
    #pragma unroll
    for (int n = 0; n < 4; ++n)
      #pragma unroll
      for (int m = 0; m < 4; ++m)
        acc[m + 4][n] = __builtin_amdgcn_mfma_f32_16x16x32_bf16(af[m], bf[n], acc[m + 4][n], 0, 0, 0);
    __builtin_amdgcn_s_setprio(0);
    asm volatile("s_barrier" ::: "memory");
  }

  #pragma unroll
  for (int fm = 0; fm < 8; ++fm) {
    #pragma unroll
    for (int fn = 0; fn < 4; ++fn) {
      int row0 = bm + wm * 128 + fm * 16 + 4 * lg;
      int col = bn + wn * 64 + fn * 16 + lr;
      #pragma unroll
      for (int i = 0; i < 4; ++i) {
        size_t idx = (size_t)(row0 + i) * N + col;
        float v = acc[fm][fn][i];
        if (EPI == 1) v += resid[idx];
        Cg[idx] = v;
      }
    }
  }
}

// ---------------- softmax over rows, summing NSPLIT partials, emit bf16 P ----
__global__ __launch_bounds__(256) void softmaxN_kernel(
    const float* __restrict__ sim, u16* __restrict__ P, int nsplit) {
  const int row = blockIdx.x;
  const int t = threadIdx.x;
  const int lane = t & 63, w = t >> 6;
  float x[8] = {0.f, 0.f, 0.f, 0.f, 0.f, 0.f, 0.f, 0.f};
  for (int s = 0; s < nsplit; ++s) {
    const float* r = sim + (size_t)s * 4194304 + (size_t)row * NROW + t * 8;
    f32x4 a0 = *(const f32x4*)(r);
    f32x4 a1 = *(const f32x4*)(r + 4);
    #pragma unroll
    for (int j = 0; j < 4; ++j) { x[j] += a0[j]; x[j + 4] += a1[j]; }
  }

  float m = x[0];
  #pragma unroll
  for (int j = 1; j < 8; ++j) m = fmaxf(m, x[j]);
  #pragma unroll
  for (int o = 1; o < 64; o <<= 1) m = fmaxf(m, __shfl_xor(m, o));
  __shared__ float redm[4], reds[4];
  if (lane == 0) redm[w] = m;
  __syncthreads();
  m = fmaxf(fmaxf(redm[0], redm[1]), fmaxf(redm[2], redm[3]));

  float e[8];
  float s = 0.f;
  #pragma unroll
  for (int j = 0; j < 8; ++j) { e[j] = __expf(x[j] - m); s += e[j]; }
  #pragma unroll
  for (int o = 1; o < 64; o <<= 1) s += __shfl_xor(s, o);
  if (lane == 0) reds[w] = s;
  __syncthreads();
  s = reds[0] + reds[1] + reds[2] + reds[3];
  float inv = 1.f / s;

  short8 pv;
  #pragma unroll
  for (int j = 0; j < 8; ++j) pv[j] = (short)f2bf(e[j] * inv);
  *(short8*)(P + (size_t)row * NROW + t * 8) = pv;
}

// ---------------- launch ----------------
extern "C" void kernel_launch(void* const* d_in, const int* in_sizes, int n_in,
                              void* d_out, int out_size, void* d_ws, size_t ws_size,
                              hipStream_t stream) {
  const float* f_in = (const float*)d_in[0];
  const float* e_in = (const float*)d_in[1];
  const float* Wq = (const float*)d_in[2];
  const float* Wk = (const float*)d_in[3];
  const float* Wv = (const float*)d_in[4];
  float* out = (float*)d_out;
  char* ws = (char*)d_ws;

  u16* wq_bf = (u16*)(ws + 0);
  u16* wk_bf = (u16*)(ws + 32768);
  u16* wv_bf = (u16*)(ws + 65536);
  u16* q    = (u16*)(ws + 98304);                        // 2048x9216 bf16
  u16* kmat = (u16*)(ws + 98304 + 37748736ull);          // 2048x9216 bf16
  u16* vt   = (u16*)(ws + 98304 + 2 * 37748736ull);      // 9216x2048 bf16 (V^T)
  float* sim = (float*)(ws + 98304 + 3 * 37748736ull);   // NSPLIT x 2048x2048 fp32
  u16* P    = q;                                         // overlay: q dead after sim GEMM

  // split-K=4 needs 180.5 MB of ws; fall back to 3 (163.7 MB, proven) if tight
  const int NSPLIT = (ws_size >= 180453376ull) ? 4 : 3;
  const int subK = HW / NSPLIT;          // 2304 or 3072
  const int NTs = subK / 32;             // 72 or 96

  wcvt_kernel<<<64, 256, 0, stream>>>(Wq, Wk, Wv, wq_bf, wk_bf, wv_bf);
  proj_kernel<<<dim3(144, 16), 256, 0, stream>>>(f_in, e_in, wq_bf, wk_bf, wv_bf, q, kmat, vt);
  // sim = q * k^T, 256^2 tiles, split-K -> 64*NSPLIT blocks (1/CU at NSPLIT=4)
  gemm8<0><<<64 * NSPLIT, 512, 0, stream>>>(q, kmat, HW, NROW, NTs, 8, 64, subK, 4194304LL, sim, nullptr);
  softmaxN_kernel<<<2048, 256, 0, stream>>>(sim, P, NSPLIT);
  // out = P * v + f_in, 8x36 = 288 blocks
  gemm8<1><<<288, 512, 0, stream>>>(P, vt, NROW, HW, 64, 36, 288, 0, 0LL, out, f_in);
}

// Round 3
// 357.786 us; speedup vs baseline: 1.1272x; 1.0034x over previous
//
#include <hip/hip_runtime.h>
#include <hip/hip_bf16.h>

typedef __attribute__((ext_vector_type(4))) float f32x4;
typedef __attribute__((ext_vector_type(8))) short short8;
typedef unsigned short u16;

typedef const __attribute__((address_space(1))) void* gas_ptr;
typedef __attribute__((address_space(3))) void* las_ptr;

#define HW 9216
#define NROW 2048
#define CCH 128

__device__ __forceinline__ u16 f2bf(float x) {
  unsigned u = __float_as_uint(x);
  u += 0x7fffu + ((u >> 16) & 1u);   // round-to-nearest-even
  return (u16)(u >> 16);
}

__device__ __forceinline__ void async16(const void* g, void* l) {
  __builtin_amdgcn_global_load_lds((gas_ptr)g, (las_ptr)l, 16, 0, 0);
}

// ---------------- kernel 0: convert weights fp32 -> bf16 ----------------
__global__ __launch_bounds__(256) void wcvt_kernel(
    const float* __restrict__ wq, const float* __restrict__ wk, const float* __restrict__ wv,
    u16* __restrict__ oq, u16* __restrict__ ok, u16* __restrict__ ov) {
  int i = blockIdx.x * 256 + threadIdx.x;
  if (i < CCH * CCH) {
    oq[i] = f2bf(wq[i]);
    ok[i] = f2bf(wk[i]);
    ov[i] = f2bf(wv[i]);
  }
}

// ---------------- kernel 1: fused projections q,k,v (unchanged) ----------------
__global__ __launch_bounds__(256) void proj_kernel(
    const float* __restrict__ f_in, const float* __restrict__ e_in,
    const u16* __restrict__ Wq, const u16* __restrict__ Wk, const u16* __restrict__ Wv,
    u16* __restrict__ q, u16* __restrict__ kmat, u16* __restrict__ vt) {
  __shared__ __align__(16) u16 Fs[64][128];
  __shared__ __align__(16) u16 Es[64][128];
  const int tid = threadIdx.x;
  const int lane = tid & 63;
  const int w = tid >> 6;
  const int b = blockIdx.y;
  const int hw0 = blockIdx.x * 64;
  const size_t base = (size_t)b * CCH * HW + hw0;

  #pragma unroll
  for (int it = 0; it < 4; ++it) {
    int g = w + 4 * it;
    const float* fp = f_in + base + (size_t)(g * 8) * HW + lane;
    const float* ep = e_in + base + (size_t)(g * 8) * HW + lane;
    short8 fv, ev;
    #pragma unroll
    for (int j = 0; j < 8; ++j) {
      fv[j] = (short)f2bf(fp[(size_t)j * HW]);
      ev[j] = (short)f2bf(ep[(size_t)j * HW]);
    }
    int gs = (g & 8) | ((g & 7) ^ (lane & 7));
    *(short8*)&Fs[lane][gs * 8] = fv;
    *(short8*)&Es[lane][gs * 8] = ev;
  }
  __syncthreads();

  const int wr = w >> 1, wc = w & 1;
  const int lr = lane & 15, lg = lane >> 4;
  f32x4 accq[4][2] = {};
  f32x4 acck[4][2] = {};
  f32x4 accv[4][2] = {};

  #pragma unroll
  for (int kk = 0; kk < 4; ++kk) {
    short8 bF[2], bE[2];
    #pragma unroll
    for (int n = 0; n < 2; ++n) {
      int col = wc * 32 + n * 16 + lr;
      int gidx = kk * 4 + lg;
      int gsw = (gidx & 8) | ((gidx & 7) ^ (col & 7));
      bF[n] = *(const short8*)&Fs[col][gsw * 8];
      bE[n] = *(const short8*)&Es[col][gsw * 8];
    }
    #pragma unroll
    for (int m = 0; m < 4; ++m) {
      int o = wr * 64 + m * 16 + lr;
      int woff = o * CCH + kk * 32 + lg * 8;
      short8 aQ = *(const short8*)(Wq + woff);
      short8 aK = *(const short8*)(Wk + woff);
      short8 aV = *(const short8*)(Wv + woff);
      #pragma unroll
      for (int n = 0; n < 2; ++n) {
        accq[m][n] = __builtin_amdgcn_mfma_f32_16x16x32_bf16(aQ, bF[n], accq[m][n], 0, 0, 0);
        acck[m][n] = __builtin_amdgcn_mfma_f32_16x16x32_bf16(aK, bE[n], acck[m][n], 0, 0, 0);
        accv[m][n] = __builtin_amdgcn_mfma_f32_16x16x32_bf16(aV, bF[n], accv[m][n], 0, 0, 0);
      }
    }
  }

  #pragma unroll
  for (int m = 0; m < 4; ++m) {
    #pragma unroll
    for (int n = 0; n < 2; ++n) {
      int o0 = wr * 64 + m * 16 + 4 * lg;
      int col = hw0 + wc * 32 + n * 16 + lr;
      int row0 = b * CCH + o0;
      #pragma unroll
      for (int i = 0; i < 4; ++i) {
        q[(size_t)(row0 + i) * HW + col] = f2bf(accq[m][n][i]);
        kmat[(size_t)(row0 + i) * HW + col] = f2bf(acck[m][n][i]);
      }
      ushort4 pv;
      pv.x = f2bf(accv[m][n][0]);
      pv.y = f2bf(accv[m][n][1]);
      pv.z = f2bf(accv[m][n][2]);
      pv.w = f2bf(accv[m][n][3]);
      *(ushort4*)&vt[(size_t)col * NROW + row0] = pv;
    }
  }
}

// ---------------- 256x256 BK=64 4-phase deep-pipelined GEMM ----------------
// C[M,N](+resid) = A[M,K] * BT[N,K]^T. 8 waves (2x4), wave tile 128x64.
// LDS: 2 buffers x 64KB. Buffer: A-half(mq) at h*8192 (128 LDS-rows x 64k),
// B-half(nq) at 16384+h*8192. Row-permuted so each half is contiguous.
// XOR swizzle: elem_col ^= (ldsrow&7)<<3 (both-sides: pre-swizzled global src).
// Per K-tile: 4 quadrant phases (mq,nq) = (0,0),(0,1),(1,1),(1,0): 16 MFMA each,
// ds_reads 12/4/8/4. Staging: pair1{A-h0,B-h0}(t+1)@P1, pair2{B-h1,A-h1}(t+1)@P2.
// Counted waits: end-P1 vmcnt(4) -> pair2(t) landed; end-P4 vmcnt(4) -> pair1(t+1).
#define BAR asm volatile("s_barrier" ::: "memory")
#define VMC4 asm volatile("s_waitcnt vmcnt(4)" ::: "memory")
#define VMC0 asm volatile("s_waitcnt vmcnt(0)" ::: "memory")

#define STG_A(h, kt) do { size_t off_ = (size_t)(h) * 64 * lda + (size_t)(kt) * 64; \
  u16* d_ = dBase + ((kt) & 1) * 32768 + (h) * 8192; \
  async16(aSrc + off_, d_); async16(aSrc + off_ + (size_t)128 * lda, d_ + 4096); } while (0)
#define STG_B(h, kt) do { size_t off_ = (size_t)(h) * 32 * lda + (size_t)(kt) * 64; \
  u16* d_ = dBase + ((kt) & 1) * 32768 + 16384 + (h) * 8192; \
  async16(bSrc + off_, d_); async16(bSrc + off_ + (size_t)128 * lda, d_ + 4096); } while (0)

#define LDA_H(mq) { const u16* p_ = smem + bb + (mq) * 8192 + (wm * 64 + lr) * 64; \
  _Pragma("unroll") for (int m_ = 0; m_ < 4; ++m_) { \
    af[m_][0] = *(const short8*)(p_ + m_ * 1024 + kof0); \
    af[m_][1] = *(const short8*)(p_ + m_ * 1024 + kof1); } }
#define LDB_H(nq) { const u16* p_ = smem + bb + 16384 + (nq) * 8192 + (wn * 32 + lr) * 64; \
  _Pragma("unroll") for (int n_ = 0; n_ < 2; ++n_) { \
    bf[n_][0] = *(const short8*)(p_ + n_ * 1024 + kof0); \
    bf[n_][1] = *(const short8*)(p_ + n_ * 1024 + kof1); } }
#define MFMA_Q(mq, nq) { \
  _Pragma("unroll") for (int n_ = 0; n_ < 2; ++n_) \
  _Pragma("unroll") for (int m_ = 0; m_ < 4; ++m_) \
  _Pragma("unroll") for (int kk_ = 0; kk_ < 2; ++kk_) \
    acc[(mq) * 4 + m_][(nq) * 2 + n_] = __builtin_amdgcn_mfma_f32_16x16x32_bf16( \
        af[m_][kk_], bf[n_][kk_], acc[(mq) * 4 + m_][(nq) * 2 + n_], 0, 0, 0); }

// MAP: XCD-chunked tile assignment (lin%8 = XCD). 0: sim NSPLIT=4 (grid 256,
// XCD = 4x8 rect of one kz); 1: PV (grid 288, XCD = 4x9 rect); 2: sim NSPLIT=3
// (grid 192, XCD = 4x2 rect per kz, kz from j).
template <int MAP, int EPI>
__global__ __launch_bounds__(512, 1) void gemm8(
    const u16* __restrict__ A, const u16* __restrict__ BT,
    int lda, int N, int NT, int kstride, long long cstride_z,
    float* __restrict__ C, const float* __restrict__ resid) {
  __shared__ __align__(16) u16 smem[65536];   // 128 KiB
  const int tid = threadIdx.x;
  const int lane = tid & 63;
  const int wid = tid >> 6;
  const int wm = wid >> 2, wn = wid & 3;
  const int lr = lane & 15, lg = lane >> 4;

  const int k = blockIdx.x & 7;
  const int j = blockIdx.x >> 3;
  int kz, by, bx;
  if (MAP == 0) { kz = k >> 1; by = (k & 1) * 4 + (j & 3); bx = j >> 2; }
  else if (MAP == 1) { kz = 0; by = (k >> 2) * 4 + (j & 3); bx = (k & 3) * 9 + (j >> 2); }
  else { kz = j >> 3; int sj = j & 7; by = (k >> 2) * 4 + (sj & 3); bx = (k & 3) * 2 + (sj >> 2); }
  const int bm = by * 256, bn = bx * 256;

  const u16* Ag = A + (size_t)kz * kstride;
  const u16* Bg = BT + (size_t)kz * kstride;
  float* Cg = C + (size_t)kz * cstride_z;

  // staging source bases (pre-swizzled col), LDS dest base (linear)
  const int r1 = tid >> 3;                                  // LDS-local row 0..63
  const int ceS = ((tid & 7) * 8) ^ ((r1 & 7) << 3);
  const u16* aSrc = Ag + (size_t)(bm + r1) * lda + ceS;
  const u16* bSrc = Bg + (size_t)(bn + ((r1 >> 5) << 6) + (r1 & 31)) * lda + ceS;
  u16* dBase = smem + tid * 8;

  // fragment read offsets (swizzled on read)
  const int kof0 = (lg * 8) ^ ((lr & 7) << 3);
  const int kof1 = (32 + lg * 8) ^ ((lr & 7) << 3);

  f32x4 acc[8][4] = {};
  short8 af[4][2], bf[2][2];

  // prologue: stage tile 0 fully (pair1 then pair2)
  STG_A(0, 0); STG_B(0, 0); STG_B(1, 0); STG_A(1, 0);
  VMC4;            // pair1(0) landed
  BAR;

  for (int t = 0; t < NT; ++t) {
    const int bb = (t & 1) * 32768;
    const bool pf = (t + 1 < NT);
    // ---- P1: quadrant (0,0) ----
    LDA_H(0); LDB_H(0);
    if (pf) { STG_A(0, t + 1); STG_B(0, t + 1); }
    BAR;
    __builtin_amdgcn_s_setprio(1);
    MFMA_Q(0, 0);
    __builtin_amdgcn_s_setprio(0);
    if (pf) { VMC4; } else { VMC0; }     // pair2(t) landed
    BAR;
    // ---- P2: quadrant (0,1) ----
    LDB_H(1);
    if (pf) { STG_B(1, t + 1); STG_A(1, t + 1); }
    BAR;
    __builtin_amdgcn_s_setprio(1);
    MFMA_Q(0, 1);
    __builtin_amdgcn_s_setprio(0);
    BAR;
    // ---- P3: quadrant (1,1) ----
    LDA_H(1);
    BAR;
    __builtin_amdgcn_s_setprio(1);
    MFMA_Q(1, 1);
    __builtin_amdgcn_s_setprio(0);
    BAR;
    // ---- P4: quadrant (1,0) ----
    LDB_H(0);
    BAR;
    __builtin_amdgcn_s_setprio(1);
    MFMA_Q(1, 0);
    __builtin_amdgcn_s_setprio(0);
    VMC4;                                 // pair1(t+1) landed
    BAR;
  }

  #pragma unroll
  for (int fm = 0; fm < 8; ++fm) {
    #pragma unroll
    for (int fn = 0; fn < 4; ++fn) {
      int row0 = bm + wm * 128 + (fm >> 2) * 64 + (fm & 3) * 16 + 4 * lg;
      int col = bn + wn * 64 + (fn >> 1) * 32 + (fn & 1) * 16 + lr;
      #pragma unroll
      for (int i = 0; i < 4; ++i) {
        size_t idx = (size_t)(row0 + i) * N + col;
        float v = acc[fm][fn][i];
        if (EPI == 1) v += resid[idx];
        Cg[idx] = v;
      }
    }
  }
}

// ---------------- softmax over rows, summing NSPLIT partials, emit bf16 P ----
__global__ __launch_bounds__(256) void softmaxN_kernel(
    const float* __restrict__ sim, u16* __restrict__ P, int nsplit) {
  const int row = blockIdx.x;
  const int t = threadIdx.x;
  const int lane = t & 63, w = t >> 6;
  float x[8] = {0.f, 0.f, 0.f, 0.f, 0.f, 0.f, 0.f, 0.f};
  for (int s = 0; s < nsplit; ++s) {
    const float* r = sim + (size_t)s * 4194304 + (size_t)row * NROW + t * 8;
    f32x4 a0 = *(const f32x4*)(r);
    f32x4 a1 = *(const f32x4*)(r + 4);
    #pragma unroll
    for (int jj = 0; jj < 4; ++jj) { x[jj] += a0[jj]; x[jj + 4] += a1[jj]; }
  }

  float m = x[0];
  #pragma unroll
  for (int jj = 1; jj < 8; ++jj) m = fmaxf(m, x[jj]);
  #pragma unroll
  for (int o = 1; o < 64; o <<= 1) m = fmaxf(m, __shfl_xor(m, o));
  __shared__ float redm[4], reds[4];
  if (lane == 0) redm[w] = m;
  __syncthreads();
  m = fmaxf(fmaxf(redm[0], redm[1]), fmaxf(redm[2], redm[3]));

  float e[8];
  float s = 0.f;
  #pragma unroll
  for (int jj = 0; jj < 8; ++jj) { e[jj] = __expf(x[jj] - m); s += e[jj]; }
  #pragma unroll
  for (int o = 1; o < 64; o <<= 1) s += __shfl_xor(s, o);
  if (lane == 0) reds[w] = s;
  __syncthreads();
  s = reds[0] + reds[1] + reds[2] + reds[3];
  float inv = 1.f / s;

  short8 pv;
  #pragma unroll
  for (int jj = 0; jj < 8; ++jj) pv[jj] = (short)f2bf(e[jj] * inv);
  *(short8*)(P + (size_t)row * NROW + t * 8) = pv;
}

// ---------------- launch ----------------
extern "C" void kernel_launch(void* const* d_in, const int* in_sizes, int n_in,
                              void* d_out, int out_size, void* d_ws, size_t ws_size,
                              hipStream_t stream) {
  const float* f_in = (const float*)d_in[0];
  const float* e_in = (const float*)d_in[1];
  const float* Wq = (const float*)d_in[2];
  const float* Wk = (const float*)d_in[3];
  const float* Wv = (const float*)d_in[4];
  float* out = (float*)d_out;
  char* ws = (char*)d_ws;

  u16* wq_bf = (u16*)(ws + 0);
  u16* wk_bf = (u16*)(ws + 32768);
  u16* wv_bf = (u16*)(ws + 65536);
  u16* q    = (u16*)(ws + 98304);                        // 2048x9216 bf16
  u16* kmat = (u16*)(ws + 98304 + 37748736ull);          // 2048x9216 bf16
  u16* vt   = (u16*)(ws + 98304 + 2 * 37748736ull);      // 9216x2048 bf16 (V^T)
  float* sim = (float*)(ws + 98304 + 3 * 37748736ull);   // NSPLIT x 2048x2048 fp32
  u16* P    = q;                                         // overlay: q dead after sim GEMM

  const int NSPLIT = (ws_size >= 180453376ull) ? 4 : 3;

  wcvt_kernel<<<64, 256, 0, stream>>>(Wq, Wk, Wv, wq_bf, wk_bf, wv_bf);
  proj_kernel<<<dim3(144, 16), 256, 0, stream>>>(f_in, e_in, wq_bf, wk_bf, wv_bf, q, kmat, vt);
  if (NSPLIT == 4)
    gemm8<0, 0><<<256, 512, 0, stream>>>(q, kmat, HW, NROW, 36, 2304, 4194304LL, sim, nullptr);
  else
    gemm8<2, 0><<<192, 512, 0, stream>>>(q, kmat, HW, NROW, 48, 3072, 4194304LL, sim, nullptr);
  softmaxN_kernel<<<2048, 256, 0, stream>>>(sim, P, NSPLIT);
  gemm8<1, 1><<<288, 512, 0, stream>>>(P, vt, NROW, HW, 32, 0, 0LL, out, f_in);
}

// Round 4
// 352.512 us; speedup vs baseline: 1.1441x; 1.0150x over previous
//
#include <hip/hip_runtime.h>
#include <hip/hip_bf16.h>

typedef __attribute__((ext_vector_type(4))) float f32x4;
typedef __attribute__((ext_vector_type(8))) short short8;
typedef unsigned short u16;

typedef const __attribute__((address_space(1))) void* gas_ptr;
typedef __attribute__((address_space(3))) void* las_ptr;

#define HW 9216
#define NROW 2048
#define CCH 128

__device__ __forceinline__ u16 f2bf(float x) {
  unsigned u = __float_as_uint(x);
  u += 0x7fffu + ((u >> 16) & 1u);   // round-to-nearest-even
  return (u16)(u >> 16);
}

__device__ __forceinline__ void async16(const void* g, void* l) {
  __builtin_amdgcn_global_load_lds((gas_ptr)g, (las_ptr)l, 16, 0, 0);
}

// ---------------- kernel 0: convert weights fp32 -> bf16 ----------------
__global__ __launch_bounds__(256) void wcvt_kernel(
    const float* __restrict__ wq, const float* __restrict__ wk, const float* __restrict__ wv,
    u16* __restrict__ oq, u16* __restrict__ ok, u16* __restrict__ ov) {
  int i = blockIdx.x * 256 + threadIdx.x;
  if (i < CCH * CCH) {
    oq[i] = f2bf(wq[i]);
    ok[i] = f2bf(wk[i]);
    ov[i] = f2bf(wv[i]);
  }
}

// ---------------- kernel 1: fused projections q,k,v (unchanged) ----------------
__global__ __launch_bounds__(256) void proj_kernel(
    const float* __restrict__ f_in, const float* __restrict__ e_in,
    const u16* __restrict__ Wq, const u16* __restrict__ Wk, const u16* __restrict__ Wv,
    u16* __restrict__ q, u16* __restrict__ kmat, u16* __restrict__ vt) {
  __shared__ __align__(16) u16 Fs[64][128];
  __shared__ __align__(16) u16 Es[64][128];
  const int tid = threadIdx.x;
  const int lane = tid & 63;
  const int w = tid >> 6;
  const int b = blockIdx.y;
  const int hw0 = blockIdx.x * 64;
  const size_t base = (size_t)b * CCH * HW + hw0;

  #pragma unroll
  for (int it = 0; it < 4; ++it) {
    int g = w + 4 * it;
    const float* fp = f_in + base + (size_t)(g * 8) * HW + lane;
    const float* ep = e_in + base + (size_t)(g * 8) * HW + lane;
    short8 fv, ev;
    #pragma unroll
    for (int j = 0; j < 8; ++j) {
      fv[j] = (short)f2bf(fp[(size_t)j * HW]);
      ev[j] = (short)f2bf(ep[(size_t)j * HW]);
    }
    int gs = (g & 8) | ((g & 7) ^ (lane & 7));
    *(short8*)&Fs[lane][gs * 8] = fv;
    *(short8*)&Es[lane][gs * 8] = ev;
  }
  __syncthreads();

  const int wr = w >> 1, wc = w & 1;
  const int lr = lane & 15, lg = lane >> 4;
  f32x4 accq[4][2] = {};
  f32x4 acck[4][2] = {};
  f32x4 accv[4][2] = {};

  #pragma unroll
  for (int kk = 0; kk < 4; ++kk) {
    short8 bF[2], bE[2];
    #pragma unroll
    for (int n = 0; n < 2; ++n) {
      int col = wc * 32 + n * 16 + lr;
      int gidx = kk * 4 + lg;
      int gsw = (gidx & 8) | ((gidx & 7) ^ (col & 7));
      bF[n] = *(const short8*)&Fs[col][gsw * 8];
      bE[n] = *(const short8*)&Es[col][gsw * 8];
    }
    #pragma unroll
    for (int m = 0; m < 4; ++m) {
      int o = wr * 64 + m * 16 + lr;
      int woff = o * CCH + kk * 32 + lg * 8;
      short8 aQ = *(const short8*)(Wq + woff);
      short8 aK = *(const short8*)(Wk + woff);
      short8 aV = *(const short8*)(Wv + woff);
      #pragma unroll
      for (int n = 0; n < 2; ++n) {
        accq[m][n] = __builtin_amdgcn_mfma_f32_16x16x32_bf16(aQ, bF[n], accq[m][n], 0, 0, 0);
        acck[m][n] = __builtin_amdgcn_mfma_f32_16x16x32_bf16(aK, bE[n], acck[m][n], 0, 0, 0);
        accv[m][n] = __builtin_amdgcn_mfma_f32_16x16x32_bf16(aV, bF[n], accv[m][n], 0, 0, 0);
      }
    }
  }

  #pragma unroll
  for (int m = 0; m < 4; ++m) {
    #pragma unroll
    for (int n = 0; n < 2; ++n) {
      int o0 = wr * 64 + m * 16 + 4 * lg;
      int col = hw0 + wc * 32 + n * 16 + lr;
      int row0 = b * CCH + o0;
      #pragma unroll
      for (int i = 0; i < 4; ++i) {
        q[(size_t)(row0 + i) * HW + col] = f2bf(accq[m][n][i]);
        kmat[(size_t)(row0 + i) * HW + col] = f2bf(acck[m][n][i]);
      }
      ushort4 pv;
      pv.x = f2bf(accv[m][n][0]);
      pv.y = f2bf(accv[m][n][1]);
      pv.z = f2bf(accv[m][n][2]);
      pv.w = f2bf(accv[m][n][3]);
      *(ushort4*)&vt[(size_t)col * NROW + row0] = pv;
    }
  }
}

// ---------------- 256x256 BK=64 2-phase deep-pipelined GEMM ----------------
// C[M,N](+resid) = A[M,K] * BT[N,K]^T. 8 waves (2x4), wave tile 128x64.
// LDS: 2 buffers x 64KB. Buffer layout: A-half(mq) at mq*8192 (128 rows x 64k),
// B-half(nq) at 16384+nq*8192. XOR swizzle: elem_col ^= (row&7)<<3, both-sides
// (pre-swizzled global source, linear LDS dest, swizzled ds_read).
// 2 phases per K-tile (4 barriers, halved vs r3 to test barrier-cost law):
//   P1: read A0 + B-full (16 ds_read_b128), stage pair1(t+1)={A0,Bfull} (6),
//       BAR, 32 MFMA (acc rows 0-3), vmcnt(6) -> A1(t) landed, BAR.
//   P2: read A1 (8 reads), stage pair2(t+1)={A1} (2),
//       BAR, 32 MFMA (acc rows 4-7), vmcnt(2) -> pair1(t+1) landed, BAR.
#define BAR asm volatile("s_barrier" ::: "memory")
#define VMC6 asm volatile("s_waitcnt vmcnt(6)" ::: "memory")
#define VMC2 asm volatile("s_waitcnt vmcnt(2)" ::: "memory")
#define VMC0 asm volatile("s_waitcnt vmcnt(0)" ::: "memory")

#define STG_A(h, kt) do { size_t off_ = (size_t)(h) * 64 * lda + (size_t)(kt) * 64; \
  u16* d_ = dBase + ((kt) & 1) * 32768 + (h) * 8192; \
  async16(aSrc + off_, d_); async16(aSrc + off_ + (size_t)128 * lda, d_ + 4096); } while (0)
#define STG_B(h, kt) do { size_t off_ = (size_t)(h) * 32 * lda + (size_t)(kt) * 64; \
  u16* d_ = dBase + ((kt) & 1) * 32768 + 16384 + (h) * 8192; \
  async16(bSrc + off_, d_); async16(bSrc + off_ + (size_t)128 * lda, d_ + 4096); } while (0)

#define LDA_H(mq) { const u16* p_ = smem + bb + (mq) * 8192 + (wm * 64 + lr) * 64; \
  _Pragma("unroll") for (int m_ = 0; m_ < 4; ++m_) { \
    af[m_][0] = *(const short8*)(p_ + m_ * 1024 + kof0); \
    af[m_][1] = *(const short8*)(p_ + m_ * 1024 + kof1); } }
#define LDB_ALL { const u16* p_ = smem + bb + 16384 + (wn * 32 + lr) * 64; \
  _Pragma("unroll") for (int h_ = 0; h_ < 2; ++h_) \
  _Pragma("unroll") for (int n_ = 0; n_ < 2; ++n_) { \
    bf[h_ * 2 + n_][0] = *(const short8*)(p_ + h_ * 8192 + n_ * 1024 + kof0); \
    bf[h_ * 2 + n_][1] = *(const short8*)(p_ + h_ * 8192 + n_ * 1024 + kof1); } }
#define MFMA_H(mq) { \
  _Pragma("unroll") for (int n_ = 0; n_ < 4; ++n_) \
  _Pragma("unroll") for (int m_ = 0; m_ < 4; ++m_) \
  _Pragma("unroll") for (int kk_ = 0; kk_ < 2; ++kk_) \
    acc[(mq) * 4 + m_][n_] = __builtin_amdgcn_mfma_f32_16x16x32_bf16( \
        af[m_][kk_], bf[n_][kk_], acc[(mq) * 4 + m_][n_], 0, 0, 0); }

// MAP: XCD-chunked tile assignment (lin%8 = XCD). 0: sim NSPLIT=4 (grid 256,
// XCD = 4x8 rect of one kz); 1: PV (grid 288, XCD = 4x9 rect); 2: sim NSPLIT=3
// (grid 192, XCD = 4x2 rect per kz, kz from j).
template <int MAP, int EPI>
__global__ __launch_bounds__(512, 1) void gemm8(
    const u16* __restrict__ A, const u16* __restrict__ BT,
    int lda, int N, int NT, int kstride, long long cstride_z,
    float* __restrict__ C, const float* __restrict__ resid) {
  __shared__ __align__(16) u16 smem[65536];   // 128 KiB
  const int tid = threadIdx.x;
  const int lane = tid & 63;
  const int wid = tid >> 6;
  const int wm = wid >> 2, wn = wid & 3;
  const int lr = lane & 15, lg = lane >> 4;

  const int k = blockIdx.x & 7;
  const int j = blockIdx.x >> 3;
  int kz, by, bx;
  if (MAP == 0) { kz = k >> 1; by = (k & 1) * 4 + (j & 3); bx = j >> 2; }
  else if (MAP == 1) { kz = 0; by = (k >> 2) * 4 + (j & 3); bx = (k & 3) * 9 + (j >> 2); }
  else { kz = j >> 3; int sj = j & 7; by = (k >> 2) * 4 + (sj & 3); bx = (k & 3) * 2 + (sj >> 2); }
  const int bm = by * 256, bn = bx * 256;

  const u16* Ag = A + (size_t)kz * kstride;
  const u16* Bg = BT + (size_t)kz * kstride;
  float* Cg = C + (size_t)kz * cstride_z;

  // staging source bases (pre-swizzled col), LDS dest base (linear)
  const int r1 = tid >> 3;                                  // LDS-local row 0..63
  const int ceS = ((tid & 7) * 8) ^ ((r1 & 7) << 3);
  const u16* aSrc = Ag + (size_t)(bm + r1) * lda + ceS;
  const u16* bSrc = Bg + (size_t)(bn + ((r1 >> 5) << 6) + (r1 & 31)) * lda + ceS;
  u16* dBase = smem + tid * 8;

  // fragment read offsets (swizzled on read)
  const int kof0 = (lg * 8) ^ ((lr & 7) << 3);
  const int kof1 = (32 + lg * 8) ^ ((lr & 7) << 3);

  f32x4 acc[8][4] = {};
  short8 af[4][2], bf[4][2];

  // prologue: stage tile 0: pair1={A0,Bfull} (6) then pair2={A1} (2)
  STG_A(0, 0); STG_B(0, 0); STG_B(1, 0); STG_A(1, 0);
  VMC2;            // pair1(0) landed
  BAR;

  for (int t = 0; t < NT; ++t) {
    const int bb = (t & 1) * 32768;
    const bool pf = (t + 1 < NT);
    // ---- P1: A-half0 x B-full (acc rows 0-3) ----
    LDA_H(0); LDB_ALL;
    if (pf) { STG_A(0, t + 1); STG_B(0, t + 1); STG_B(1, t + 1); }
    BAR;
    __builtin_amdgcn_s_setprio(1);
    MFMA_H(0);
    __builtin_amdgcn_s_setprio(0);
    if (pf) { VMC6; } else { VMC0; }     // A1(t) landed
    BAR;
    // ---- P2: A-half1 x B-full (acc rows 4-7) ----
    LDA_H(1);
    if (pf) { STG_A(1, t + 1); }
    BAR;
    __builtin_amdgcn_s_setprio(1);
    MFMA_H(1);
    __builtin_amdgcn_s_setprio(0);
    if (pf) { VMC2; }                    // pair1(t+1) landed
    BAR;
  }

  #pragma unroll
  for (int fm = 0; fm < 8; ++fm) {
    #pragma unroll
    for (int fn = 0; fn < 4; ++fn) {
      int row0 = bm + wm * 128 + (fm >> 2) * 64 + (fm & 3) * 16 + 4 * lg;
      int col = bn + wn * 64 + (fn >> 1) * 32 + (fn & 1) * 16 + lr;
      #pragma unroll
      for (int i = 0; i < 4; ++i) {
        size_t idx = (size_t)(row0 + i) * N + col;
        float v = acc[fm][fn][i];
        if (EPI == 1) v += resid[idx];
        Cg[idx] = v;
      }
    }
  }
}

// ---------------- softmax over rows, summing NSPLIT partials, emit bf16 P ----
__global__ __launch_bounds__(256) void softmaxN_kernel(
    const float* __restrict__ sim, u16* __restrict__ P, int nsplit) {
  const int row = blockIdx.x;
  const int t = threadIdx.x;
  const int lane = t & 63, w = t >> 6;
  float x[8] = {0.f, 0.f, 0.f, 0.f, 0.f, 0.f, 0.f, 0.f};
  for (int s = 0; s < nsplit; ++s) {
    const float* r = sim + (size_t)s * 4194304 + (size_t)row * NROW + t * 8;
    f32x4 a0 = *(const f32x4*)(r);
    f32x4 a1 = *(const f32x4*)(r + 4);
    #pragma unroll
    for (int jj = 0; jj < 4; ++jj) { x[jj] += a0[jj]; x[jj + 4] += a1[jj]; }
  }

  float m = x[0];
  #pragma unroll
  for (int jj = 1; jj < 8; ++jj) m = fmaxf(m, x[jj]);
  #pragma unroll
  for (int o = 1; o < 64; o <<= 1) m = fmaxf(m, __shfl_xor(m, o));
  __shared__ float redm[4], reds[4];
  if (lane == 0) redm[w] = m;
  __syncthreads();
  m = fmaxf(fmaxf(redm[0], redm[1]), fmaxf(redm[2], redm[3]));

  float e[8];
  float s = 0.f;
  #pragma unroll
  for (int jj = 0; jj < 8; ++jj) { e[jj] = __expf(x[jj] - m); s += e[jj]; }
  #pragma unroll
  for (int o = 1; o < 64; o <<= 1) s += __shfl_xor(s, o);
  if (lane == 0) reds[w] = s;
  __syncthreads();
  s = reds[0] + reds[1] + reds[2] + reds[3];
  float inv = 1.f / s;

  short8 pv;
  #pragma unroll
  for (int jj = 0; jj < 8; ++jj) pv[jj] = (short)f2bf(e[jj] * inv);
  *(short8*)(P + (size_t)row * NROW + t * 8) = pv;
}

// ---------------- launch ----------------
extern "C" void kernel_launch(void* const* d_in, const int* in_sizes, int n_in,
                              void* d_out, int out_size, void* d_ws, size_t ws_size,
                              hipStream_t stream) {
  const float* f_in = (const float*)d_in[0];
  const float* e_in = (const float*)d_in[1];
  const float* Wq = (const float*)d_in[2];
  const float* Wk = (const float*)d_in[3];
  const float* Wv = (const float*)d_in[4];
  float* out = (float*)d_out;
  char* ws = (char*)d_ws;

  u16* wq_bf = (u16*)(ws + 0);
  u16* wk_bf = (u16*)(ws + 32768);
  u16* wv_bf = (u16*)(ws + 65536);
  u16* q    = (u16*)(ws + 98304);                        // 2048x9216 bf16
  u16* kmat = (u16*)(ws + 98304 + 37748736ull);          // 2048x9216 bf16
  u16* vt   = (u16*)(ws + 98304 + 2 * 37748736ull);      // 9216x2048 bf16 (V^T)
  float* sim = (float*)(ws + 98304 + 3 * 37748736ull);   // NSPLIT x 2048x2048 fp32
  u16* P    = q;                                         // overlay: q dead after sim GEMM

  const int NSPLIT = (ws_size >= 180453376ull) ? 4 : 3;

  wcvt_kernel<<<64, 256, 0, stream>>>(Wq, Wk, Wv, wq_bf, wk_bf, wv_bf);
  proj_kernel<<<dim3(144, 16), 256, 0, stream>>>(f_in, e_in, wq_bf, wk_bf, wv_bf, q, kmat, vt);
  if (NSPLIT == 4)
    gemm8<0, 0><<<256, 512, 0, stream>>>(q, kmat, HW, NROW, 36, 2304, 4194304LL, sim, nullptr);
  else
    gemm8<2, 0><<<192, 512, 0, stream>>>(q, kmat, HW, NROW, 48, 3072, 4194304LL, sim, nullptr);
  softmaxN_kernel<<<2048, 256, 0, stream>>>(sim, P, NSPLIT);
  gemm8<1, 1><<<288, 512, 0, stream>>>(P, vt, NROW, HW, 32, 0, 0LL, out, f_in);
}

// Round 5
// 320.090 us; speedup vs baseline: 1.2599x; 1.1013x over previous
//
#include <hip/hip_runtime.h>
#include <hip/hip_bf16.h>

typedef __attribute__((ext_vector_type(4))) float f32x4;
typedef __attribute__((ext_vector_type(8))) short short8;
typedef unsigned short u16;

typedef const __attribute__((address_space(1))) void* gas_ptr;
typedef __attribute__((address_space(3))) void* las_ptr;

#define HW 9216
#define NROW 2048
#define CCH 128

__device__ __forceinline__ u16 f2bf(float x) {
  unsigned u = __float_as_uint(x);
  u += 0x7fffu + ((u >> 16) & 1u);   // round-to-nearest-even
  return (u16)(u >> 16);
}

__device__ __forceinline__ void async16(const void* g, void* l) {
  __builtin_amdgcn_global_load_lds((gas_ptr)g, (las_ptr)l, 16, 0, 0);
}

// ---------------- kernel 0: convert weights fp32 -> bf16 ----------------
__global__ __launch_bounds__(256) void wcvt_kernel(
    const float* __restrict__ wq, const float* __restrict__ wk, const float* __restrict__ wv,
    u16* __restrict__ oq, u16* __restrict__ ok, u16* __restrict__ ov) {
  int i = blockIdx.x * 256 + threadIdx.x;
  if (i < CCH * CCH) {
    oq[i] = f2bf(wq[i]);
    ok[i] = f2bf(wk[i]);
    ov[i] = f2bf(wv[i]);
  }
}

// ---------------- kernel 1: fused projections q,k,v (unchanged) ----------------
__global__ __launch_bounds__(256) void proj_kernel(
    const float* __restrict__ f_in, const float* __restrict__ e_in,
    const u16* __restrict__ Wq, const u16* __restrict__ Wk, const u16* __restrict__ Wv,
    u16* __restrict__ q, u16* __restrict__ kmat, u16* __restrict__ vt) {
  __shared__ __align__(16) u16 Fs[64][128];
  __shared__ __align__(16) u16 Es[64][128];
  const int tid = threadIdx.x;
  const int lane = tid & 63;
  const int w = tid >> 6;
  const int b = blockIdx.y;
  const int hw0 = blockIdx.x * 64;
  const size_t base = (size_t)b * CCH * HW + hw0;

  #pragma unroll
  for (int it = 0; it < 4; ++it) {
    int g = w + 4 * it;
    const float* fp = f_in + base + (size_t)(g * 8) * HW + lane;
    const float* ep = e_in + base + (size_t)(g * 8) * HW + lane;
    short8 fv, ev;
    #pragma unroll
    for (int j = 0; j < 8; ++j) {
      fv[j] = (short)f2bf(fp[(size_t)j * HW]);
      ev[j] = (short)f2bf(ep[(size_t)j * HW]);
    }
    int gs = (g & 8) | ((g & 7) ^ (lane & 7));
    *(short8*)&Fs[lane][gs * 8] = fv;
    *(short8*)&Es[lane][gs * 8] = ev;
  }
  __syncthreads();

  const int wr = w >> 1, wc = w & 1;
  const int lr = lane & 15, lg = lane >> 4;
  f32x4 accq[4][2] = {};
  f32x4 acck[4][2] = {};
  f32x4 accv[4][2] = {};

  #pragma unroll
  for (int kk = 0; kk < 4; ++kk) {
    short8 bF[2], bE[2];
    #pragma unroll
    for (int n = 0; n < 2; ++n) {
      int col = wc * 32 + n * 16 + lr;
      int gidx = kk * 4 + lg;
      int gsw = (gidx & 8) | ((gidx & 7) ^ (col & 7));
      bF[n] = *(const short8*)&Fs[col][gsw * 8];
      bE[n] = *(const short8*)&Es[col][gsw * 8];
    }
    #pragma unroll
    for (int m = 0; m < 4; ++m) {
      int o = wr * 64 + m * 16 + lr;
      int woff = o * CCH + kk * 32 + lg * 8;
      short8 aQ = *(const short8*)(Wq + woff);
      short8 aK = *(const short8*)(Wk + woff);
      short8 aV = *(const short8*)(Wv + woff);
      #pragma unroll
      for (int n = 0; n < 2; ++n) {
        accq[m][n] = __builtin_amdgcn_mfma_f32_16x16x32_bf16(aQ, bF[n], accq[m][n], 0, 0, 0);
        acck[m][n] = __builtin_amdgcn_mfma_f32_16x16x32_bf16(aK, bE[n], acck[m][n], 0, 0, 0);
        accv[m][n] = __builtin_amdgcn_mfma_f32_16x16x32_bf16(aV, bF[n], accv[m][n], 0, 0, 0);
      }
    }
  }

  #pragma unroll
  for (int m = 0; m < 4; ++m) {
    #pragma unroll
    for (int n = 0; n < 2; ++n) {
      int o0 = wr * 64 + m * 16 + 4 * lg;
      int col = hw0 + wc * 32 + n * 16 + lr;
      int row0 = b * CCH + o0;
      #pragma unroll
      for (int i = 0; i < 4; ++i) {
        q[(size_t)(row0 + i) * HW + col] = f2bf(accq[m][n][i]);
        kmat[(size_t)(row0 + i) * HW + col] = f2bf(acck[m][n][i]);
      }
      ushort4 pv;
      pv.x = f2bf(accv[m][n][0]);
      pv.y = f2bf(accv[m][n][1]);
      pv.z = f2bf(accv[m][n][2]);
      pv.w = f2bf(accv[m][n][3]);
      *(ushort4*)&vt[(size_t)col * NROW + row0] = pv;
    }
  }
}

// ---------------- 128x128 BK=64 single-buffer GEMM, 3+ blocks/CU ----------------
// C[M,N](+resid) = A[M,K] * BT[N,K]^T. 4 waves (2x2), wave tile 64x64.
// LDS 32KB single buffer: A [128 rows][64k] at 0, B at 8192 (u16 elems).
// XOR swizzle: 16B-slot s -> s ^ (row&7), both-sides (pre-swizzled global src,
// linear LDS dest, swizzled ds_read). m97-style loop: stage; sync; read+MFMA; sync.
// Cross-block overlap (3 blocks/CU) hides the stage drain - no intra-block pipelining.
template <int MAP, int EPI>
__global__ __launch_bounds__(256, 3) void gemm4(
    const u16* __restrict__ A, const u16* __restrict__ BT,
    int lda, int N, int NT, int kstride, long long cstride_z,
    float* __restrict__ C, const float* __restrict__ resid) {
  __shared__ __align__(16) u16 smem[16384];   // 32 KiB
  const int tid = threadIdx.x;
  const int lane = tid & 63;
  const int wid = tid >> 6;
  const int wm = wid >> 1, wn = wid & 1;
  const int lr = lane & 15, lg = lane >> 4;

  // XCD-chunked tile maps (blockIdx.x & 7 = XCD)
  const int k = blockIdx.x & 7;
  const int j = blockIdx.x >> 3;
  int kz, by, bx;
  if (MAP == 0) {        // sim NSPLIT=4: grid 1024; XCD = 8by x 16bx of one kz
    kz = k >> 1; by = (k & 1) * 8 + (j & 7); bx = j >> 3;
  } else if (MAP == 1) { // PV: grid 1152 (16by x 72bx); XCD = 8by x 18bx
    kz = 0; by = (k >> 2) * 8 + (j & 7); bx = (k & 3) * 18 + (j >> 3);
  } else {               // sim NSPLIT=3: grid 768; XCD = 8by x 4bx across 3 kz
    kz = j % 3; int rest = j / 3;
    by = (k & 1) * 8 + (rest & 7); bx = (k >> 1) * 4 + (rest >> 3);
  }
  const int bm = by * 128, bn = bx * 128;

  const u16* Ag = A + (size_t)kz * kstride;
  const u16* Bg = BT + (size_t)kz * kstride;
  float* Cg = C + (size_t)kz * cstride_z;

  // staging: 1024 16B-chunks per matrix; chunk q = tid + 256*i; row=q>>3, slot=q&7
  // source col pre-swizzled (slot ^ row&7), LDS dest linear.
  const u16* aS[4];
  const u16* bS[4];
  u16* dA[4];
  u16* dB[4];
  #pragma unroll
  for (int i = 0; i < 4; ++i) {
    int qq = tid + 256 * i;
    int row = qq >> 3, slot = qq & 7;
    int ce = (slot ^ (row & 7)) * 8;
    aS[i] = Ag + (size_t)(bm + row) * lda + ce;
    bS[i] = Bg + (size_t)(bn + row) * lda + ce;
    dA[i] = smem + qq * 8;
    dB[i] = smem + 8192 + qq * 8;
  }

  // fragment read offsets (swizzled on read); slot kk*4+lg -> ^(lr&7)
  const int kof0 = (lg * 8) ^ ((lr & 7) << 3);
  const int kof1 = (32 + lg * 8) ^ ((lr & 7) << 3);

  f32x4 acc[4][4] = {};

  for (int t = 0; t < NT; ++t) {
    const size_t ko = (size_t)t * 64;
    #pragma unroll
    for (int i = 0; i < 4; ++i) { async16(aS[i] + ko, dA[i]); async16(bS[i] + ko, dB[i]); }
    __syncthreads();                  // drains vmcnt -> tile visible to all waves
    short8 a[4][2], b[4][2];
    #pragma unroll
    for (int m = 0; m < 4; ++m) {
      const u16* p = smem + (wm * 64 + m * 16 + lr) * 64;
      a[m][0] = *(const short8*)(p + kof0);
      a[m][1] = *(const short8*)(p + kof1);
    }
    #pragma unroll
    for (int n = 0; n < 4; ++n) {
      const u16* p = smem + 8192 + (wn * 64 + n * 16 + lr) * 64;
      b[n][0] = *(const short8*)(p + kof0);
      b[n][1] = *(const short8*)(p + kof1);
    }
    #pragma unroll
    for (int kk = 0; kk < 2; ++kk)      // kk outermost: 16 independent MFMAs between repeats
      #pragma unroll
      for (int m = 0; m < 4; ++m)
        #pragma unroll
        for (int n = 0; n < 4; ++n)
          acc[m][n] = __builtin_amdgcn_mfma_f32_16x16x32_bf16(a[m][kk], b[n][kk], acc[m][n], 0, 0, 0);
    __syncthreads();                  // reads consumed before next stage overwrites
  }

  #pragma unroll
  for (int m = 0; m < 4; ++m) {
    #pragma unroll
    for (int n = 0; n < 4; ++n) {
      int row0 = bm + wm * 64 + m * 16 + 4 * lg;
      int col = bn + wn * 64 + n * 16 + lr;
      #pragma unroll
      for (int i = 0; i < 4; ++i) {
        size_t idx = (size_t)(row0 + i) * N + col;
        float v = acc[m][n][i];
        if (EPI == 1) v += resid[idx];
        Cg[idx] = v;
      }
    }
  }
}

// ---------------- softmax over rows, summing NSPLIT partials, emit bf16 P ----
__global__ __launch_bounds__(256) void softmaxN_kernel(
    const float* __restrict__ sim, u16* __restrict__ P, int nsplit) {
  const int row = blockIdx.x;
  const int t = threadIdx.x;
  const int lane = t & 63, w = t >> 6;
  float x[8] = {0.f, 0.f, 0.f, 0.f, 0.f, 0.f, 0.f, 0.f};
  for (int s = 0; s < nsplit; ++s) {
    const float* r = sim + (size_t)s * 4194304 + (size_t)row * NROW + t * 8;
    f32x4 a0 = *(const f32x4*)(r);
    f32x4 a1 = *(const f32x4*)(r + 4);
    #pragma unroll
    for (int jj = 0; jj < 4; ++jj) { x[jj] += a0[jj]; x[jj + 4] += a1[jj]; }
  }

  float m = x[0];
  #pragma unroll
  for (int jj = 1; jj < 8; ++jj) m = fmaxf(m, x[jj]);
  #pragma unroll
  for (int o = 1; o < 64; o <<= 1) m = fmaxf(m, __shfl_xor(m, o));
  __shared__ float redm[4], reds[4];
  if (lane == 0) redm[w] = m;
  __syncthreads();
  m = fmaxf(fmaxf(redm[0], redm[1]), fmaxf(redm[2], redm[3]));

  float e[8];
  float s = 0.f;
  #pragma unroll
  for (int jj = 0; jj < 8; ++jj) { e[jj] = __expf(x[jj] - m); s += e[jj]; }
  #pragma unroll
  for (int o = 1; o < 64; o <<= 1) s += __shfl_xor(s, o);
  if (lane == 0) reds[w] = s;
  __syncthreads();
  s = reds[0] + reds[1] + reds[2] + reds[3];
  float inv = 1.f / s;

  short8 pv;
  #pragma unroll
  for (int jj = 0; jj < 8; ++jj) pv[jj] = (short)f2bf(e[jj] * inv);
  *(short8*)(P + (size_t)row * NROW + t * 8) = pv;
}

// ---------------- launch ----------------
extern "C" void kernel_launch(void* const* d_in, const int* in_sizes, int n_in,
                              void* d_out, int out_size, void* d_ws, size_t ws_size,
                              hipStream_t stream) {
  const float* f_in = (const float*)d_in[0];
  const float* e_in = (const float*)d_in[1];
  const float* Wq = (const float*)d_in[2];
  const float* Wk = (const float*)d_in[3];
  const float* Wv = (const float*)d_in[4];
  float* out = (float*)d_out;
  char* ws = (char*)d_ws;

  u16* wq_bf = (u16*)(ws + 0);
  u16* wk_bf = (u16*)(ws + 32768);
  u16* wv_bf = (u16*)(ws + 65536);
  u16* q    = (u16*)(ws + 98304);                        // 2048x9216 bf16
  u16* kmat = (u16*)(ws + 98304 + 37748736ull);          // 2048x9216 bf16
  u16* vt   = (u16*)(ws + 98304 + 2 * 37748736ull);      // 9216x2048 bf16 (V^T)
  float* sim = (float*)(ws + 98304 + 3 * 37748736ull);   // NSPLIT x 2048x2048 fp32
  u16* P    = q;                                         // overlay: q dead after sim GEMM

  const int NSPLIT = (ws_size >= 180453376ull) ? 4 : 3;

  wcvt_kernel<<<64, 256, 0, stream>>>(Wq, Wk, Wv, wq_bf, wk_bf, wv_bf);
  proj_kernel<<<dim3(144, 16), 256, 0, stream>>>(f_in, e_in, wq_bf, wk_bf, wv_bf, q, kmat, vt);
  if (NSPLIT == 4)
    gemm4<0, 0><<<1024, 256, 0, stream>>>(q, kmat, HW, NROW, 36, 2304, 4194304LL, sim, nullptr);
  else
    gemm4<2, 0><<<768, 256, 0, stream>>>(q, kmat, HW, NROW, 48, 3072, 4194304LL, sim, nullptr);
  softmaxN_kernel<<<2048, 256, 0, stream>>>(sim, P, NSPLIT);
  gemm4<1, 1><<<1152, 256, 0, stream>>>(P, vt, NROW, HW, 32, 0, 0LL, out, f_in);
}

// Round 7
// 256.782 us; speedup vs baseline: 1.5706x; 1.2465x over previous
//
#include <hip/hip_runtime.h>
#include <hip/hip_bf16.h>

typedef __attribute__((ext_vector_type(4))) float f32x4;
typedef __attribute__((ext_vector_type(8))) short short8;
typedef unsigned short u16;

typedef const __attribute__((address_space(1))) void* gas_ptr;
typedef __attribute__((address_space(3))) void* las_ptr;

#define HW 9216
#define NROW 2048
#define CCH 128

__device__ __forceinline__ u16 f2bf(float x) {
  unsigned u = __float_as_uint(x);
  u += 0x7fffu + ((u >> 16) & 1u);   // round-to-nearest-even
  return (u16)(u >> 16);
}

__device__ __forceinline__ void async16(const void* g, void* l) {
  __builtin_amdgcn_global_load_lds((gas_ptr)g, (las_ptr)l, 16, 0, 0);
}

// ---------------- kernel 0: convert weights fp32 -> bf16 ----------------
__global__ __launch_bounds__(256) void wcvt_kernel(
    const float* __restrict__ wq, const float* __restrict__ wk, const float* __restrict__ wv,
    u16* __restrict__ oq, u16* __restrict__ ok, u16* __restrict__ ov) {
  int i = blockIdx.x * 256 + threadIdx.x;
  if (i < CCH * CCH) {
    oq[i] = f2bf(wq[i]);
    ok[i] = f2bf(wk[i]);
    ov[i] = f2bf(wv[i]);
  }
}

// ---------------- kernel 1 v2: projection, one of {q,k,v} per blockIdx.z ----
// z=0: q = Wq*f (row-major out); z=1: k = Wk*e; z=2: vt = (Wv*f)^T.
// Block: 128 o x 64 hw, 4 waves = 4 o-bands of 32. W a-frags preloaded to
// registers BEFORE staging (latency hidden under staging loads). Outputs
// staged through LDS for coalesced 16B/lane global stores (incl. transpose).
// r7 fix: q/k store loop was i<2 with 16-elem chunk spacing (half the columns
// never written). Correct geometry: 1024 chunks, r=L>>3, ch=L&7, spacing 8.
__global__ __launch_bounds__(256) void proj2_kernel(
    const float* __restrict__ f_in, const float* __restrict__ e_in,
    const u16* __restrict__ Wq, const u16* __restrict__ Wk, const u16* __restrict__ Wv,
    u16* __restrict__ q, u16* __restrict__ kmat, u16* __restrict__ vt) {
  __shared__ __align__(16) u16 smem[9216];   // 18KB: max(stage 64x128, out 128x72, outT 64x136)
  const int tid = threadIdx.x;
  const int lane = tid & 63;
  const int w = tid >> 6;                    // wave = o-band (32 rows)
  const int lr = lane & 15, lg = lane >> 4;
  const int z = blockIdx.z;
  const int b = blockIdx.y;
  const int hw0 = blockIdx.x * 64;

  const float* src = (z == 1) ? e_in : f_in;
  const u16* W = (z == 0) ? Wq : (z == 1) ? Wk : Wv;

  // preload W a-frags (o = w*32 + m*16 + lr, c = kk*32 + lg*8 ..+8)
  short8 afrag[2][4];
  #pragma unroll
  for (int m = 0; m < 2; ++m)
    #pragma unroll
    for (int kk = 0; kk < 4; ++kk)
      afrag[m][kk] = *(const short8*)(W + (w * 32 + m * 16 + lr) * CCH + kk * 32 + lg * 8);

  // stage src tile [64 hw][128 c] swizzled (proven r1 pattern, one matrix)
  const size_t base = (size_t)b * CCH * HW + hw0;
  #pragma unroll
  for (int it = 0; it < 4; ++it) {
    int g = w + 4 * it;                      // c-block 0..15 (8 channels each)
    const float* sp = src + base + (size_t)(g * 8) * HW + lane;
    short8 sv;
    #pragma unroll
    for (int j = 0; j < 8; ++j) sv[j] = (short)f2bf(sp[(size_t)j * HW]);
    int gs = (g & 8) | ((g & 7) ^ (lane & 7));
    *(short8*)&smem[lane * 128 + gs * 8] = sv;
  }
  __syncthreads();

  f32x4 acc[2][4] = {};
  #pragma unroll
  for (int kk = 0; kk < 4; ++kk) {
    short8 bF[4];
    #pragma unroll
    for (int n = 0; n < 4; ++n) {
      int col = n * 16 + lr;
      int gidx = kk * 4 + lg;
      int gsw = (gidx & 8) | ((gidx & 7) ^ (col & 7));
      bF[n] = *(const short8*)&smem[col * 128 + gsw * 8];
    }
    #pragma unroll
    for (int m = 0; m < 2; ++m)
      #pragma unroll
      for (int n = 0; n < 4; ++n)
        acc[m][n] = __builtin_amdgcn_mfma_f32_16x16x32_bf16(afrag[m][kk], bF[n], acc[m][n], 0, 0, 0);
  }
  __syncthreads();   // all reads of staged tile done; reuse smem for output

  if (z < 2) {
    // stage [128 o][stride 72] bf16 (2-way bank at worst), then coalesced stores
    #pragma unroll
    for (int m = 0; m < 2; ++m)
      #pragma unroll
      for (int n = 0; n < 4; ++n) {
        int o0 = w * 32 + m * 16 + 4 * lg;
        int col = n * 16 + lr;
        #pragma unroll
        for (int i = 0; i < 4; ++i)
          smem[(o0 + i) * 72 + col] = f2bf(acc[m][n][i]);
      }
    __syncthreads();
    u16* dst = (z == 0) ? q : kmat;
    #pragma unroll
    for (int i = 0; i < 4; ++i) {
      int L = tid + 256 * i;                 // 0..1023: 128 rows x 8 chunks of 8
      int r = L >> 3, ch = L & 7;
      short8 vv = *(const short8*)&smem[r * 72 + ch * 8];
      *(short8*)&dst[(size_t)(b * CCH + r) * HW + hw0 + ch * 8] = vv;
    }
  } else {
    // stage transposed [64 hw][stride 136] via ushort4 writes, coalesced stores
    #pragma unroll
    for (int m = 0; m < 2; ++m)
      #pragma unroll
      for (int n = 0; n < 4; ++n) {
        int o0 = w * 32 + m * 16 + 4 * lg;
        int col = n * 16 + lr;
        ushort4 pv;
        pv.x = f2bf(acc[m][n][0]);
        pv.y = f2bf(acc[m][n][1]);
        pv.z = f2bf(acc[m][n][2]);
        pv.w = f2bf(acc[m][n][3]);
        *(ushort4*)&smem[col * 136 + o0] = pv;
      }
    __syncthreads();
    #pragma unroll
    for (int i = 0; i < 4; ++i) {
      int L = tid + 256 * i;                 // 0..1023: 64 rows x 16 chunks of 8
      int hw = L >> 4, ch = L & 15;
      short8 vv = *(const short8*)&smem[hw * 136 + ch * 8];
      *(short8*)&vt[(size_t)(hw0 + hw) * NROW + b * CCH + ch * 8] = vv;
    }
  }
}

// ---------------- 128x128 BK=64 single-buffer GEMM, 3+ blocks/CU (r5 winner) ----
template <int MAP, int EPI>
__global__ __launch_bounds__(256, 3) void gemm4(
    const u16* __restrict__ A, const u16* __restrict__ BT,
    int lda, int N, int NT, int kstride, long long cstride_z,
    float* __restrict__ C, const float* __restrict__ resid) {
  __shared__ __align__(16) u16 smem[16384];   // 32 KiB
  const int tid = threadIdx.x;
  const int lane = tid & 63;
  const int wid = tid >> 6;
  const int wm = wid >> 1, wn = wid & 1;
  const int lr = lane & 15, lg = lane >> 4;

  // XCD-chunked tile maps (blockIdx.x & 7 = XCD)
  const int k = blockIdx.x & 7;
  const int j = blockIdx.x >> 3;
  int kz, by, bx;
  if (MAP == 0) {        // sim NSPLIT=4: grid 1024; XCD = 8by x 16bx of one kz
    kz = k >> 1; by = (k & 1) * 8 + (j & 7); bx = j >> 3;
  } else if (MAP == 1) { // PV: grid 1152 (16by x 72bx); XCD = 8by x 18bx
    kz = 0; by = (k >> 2) * 8 + (j & 7); bx = (k & 3) * 18 + (j >> 3);
  } else {               // sim NSPLIT=3: grid 768; XCD = 8by x 4bx across 3 kz
    kz = j % 3; int rest = j / 3;
    by = (k & 1) * 8 + (rest & 7); bx = (k >> 1) * 4 + (rest >> 3);
  }
  const int bm = by * 128, bn = bx * 128;

  const u16* Ag = A + (size_t)kz * kstride;
  const u16* Bg = BT + (size_t)kz * kstride;
  float* Cg = C + (size_t)kz * cstride_z;

  // staging: 1024 16B-chunks per matrix; chunk q = tid + 256*i; row=q>>3, slot=q&7
  const u16* aS[4];
  const u16* bS[4];
  u16* dA[4];
  u16* dB[4];
  #pragma unroll
  for (int i = 0; i < 4; ++i) {
    int qq = tid + 256 * i;
    int row = qq >> 3, slot = qq & 7;
    int ce = (slot ^ (row & 7)) * 8;
    aS[i] = Ag + (size_t)(bm + row) * lda + ce;
    bS[i] = Bg + (size_t)(bn + row) * lda + ce;
    dA[i] = smem + qq * 8;
    dB[i] = smem + 8192 + qq * 8;
  }

  const int kof0 = (lg * 8) ^ ((lr & 7) << 3);
  const int kof1 = (32 + lg * 8) ^ ((lr & 7) << 3);

  f32x4 acc[4][4] = {};

  for (int t = 0; t < NT; ++t) {
    const size_t ko = (size_t)t * 64;
    #pragma unroll
    for (int i = 0; i < 4; ++i) { async16(aS[i] + ko, dA[i]); async16(bS[i] + ko, dB[i]); }
    __syncthreads();
    short8 a[4][2], b[4][2];
    #pragma unroll
    for (int m = 0; m < 4; ++m) {
      const u16* p = smem + (wm * 64 + m * 16 + lr) * 64;
      a[m][0] = *(const short8*)(p + kof0);
      a[m][1] = *(const short8*)(p + kof1);
    }
    #pragma unroll
    for (int n = 0; n < 4; ++n) {
      const u16* p = smem + 8192 + (wn * 64 + n * 16 + lr) * 64;
      b[n][0] = *(const short8*)(p + kof0);
      b[n][1] = *(const short8*)(p + kof1);
    }
    #pragma unroll
    for (int kk = 0; kk < 2; ++kk)
      #pragma unroll
      for (int m = 0; m < 4; ++m)
        #pragma unroll
        for (int n = 0; n < 4; ++n)
          acc[m][n] = __builtin_amdgcn_mfma_f32_16x16x32_bf16(a[m][kk], b[n][kk], acc[m][n], 0, 0, 0);
    __syncthreads();
  }

  #pragma unroll
  for (int m = 0; m < 4; ++m) {
    #pragma unroll
    for (int n = 0; n < 4; ++n) {
      int row0 = bm + wm * 64 + m * 16 + 4 * lg;
      int col = bn + wn * 64 + n * 16 + lr;
      #pragma unroll
      for (int i = 0; i < 4; ++i) {
        size_t idx = (size_t)(row0 + i) * N + col;
        float v = acc[m][n][i];
        if (EPI == 1) v += resid[idx];
        Cg[idx] = v;
      }
    }
  }
}

// ---------------- softmax over rows, summing NSPLIT partials, emit bf16 P ----
__global__ __launch_bounds__(256) void softmaxN_kernel(
    const float* __restrict__ sim, u16* __restrict__ P, int nsplit) {
  const int row = blockIdx.x;
  const int t = threadIdx.x;
  const int lane = t & 63, w = t >> 6;
  float x[8] = {0.f, 0.f, 0.f, 0.f, 0.f, 0.f, 0.f, 0.f};
  for (int s = 0; s < nsplit; ++s) {
    const float* r = sim + (size_t)s * 4194304 + (size_t)row * NROW + t * 8;
    f32x4 a0 = *(const f32x4*)(r);
    f32x4 a1 = *(const f32x4*)(r + 4);
    #pragma unroll
    for (int jj = 0; jj < 4; ++jj) { x[jj] += a0[jj]; x[jj + 4] += a1[jj]; }
  }

  float m = x[0];
  #pragma unroll
  for (int jj = 1; jj < 8; ++jj) m = fmaxf(m, x[jj]);
  #pragma unroll
  for (int o = 1; o < 64; o <<= 1) m = fmaxf(m, __shfl_xor(m, o));
  __shared__ float redm[4], reds[4];
  if (lane == 0) redm[w] = m;
  __syncthreads();
  m = fmaxf(fmaxf(redm[0], redm[1]), fmaxf(redm[2], redm[3]));

  float e[8];
  float s = 0.f;
  #pragma unroll
  for (int jj = 0; jj < 8; ++jj) { e[jj] = __expf(x[jj] - m); s += e[jj]; }
  #pragma unroll
  for (int o = 1; o < 64; o <<= 1) s += __shfl_xor(s, o);
  if (lane == 0) reds[w] = s;
  __syncthreads();
  s = reds[0] + reds[1] + reds[2] + reds[3];
  float inv = 1.f / s;

  short8 pv;
  #pragma unroll
  for (int jj = 0; jj < 8; ++jj) pv[jj] = (short)f2bf(e[jj] * inv);
  *(short8*)(P + (size_t)row * NROW + t * 8) = pv;
}

// ---------------- launch ----------------
extern "C" void kernel_launch(void* const* d_in, const int* in_sizes, int n_in,
                              void* d_out, int out_size, void* d_ws, size_t ws_size,
                              hipStream_t stream) {
  const float* f_in = (const float*)d_in[0];
  const float* e_in = (const float*)d_in[1];
  const float* Wq = (const float*)d_in[2];
  const float* Wk = (const float*)d_in[3];
  const float* Wv = (const float*)d_in[4];
  float* out = (float*)d_out;
  char* ws = (char*)d_ws;

  u16* wq_bf = (u16*)(ws + 0);
  u16* wk_bf = (u16*)(ws + 32768);
  u16* wv_bf = (u16*)(ws + 65536);
  u16* q    = (u16*)(ws + 98304);                        // 2048x9216 bf16
  u16* kmat = (u16*)(ws + 98304 + 37748736ull);          // 2048x9216 bf16
  u16* vt   = (u16*)(ws + 98304 + 2 * 37748736ull);      // 9216x2048 bf16 (V^T)
  float* sim = (float*)(ws + 98304 + 3 * 37748736ull);   // NSPLIT x 2048x2048 fp32
  u16* P    = q;                                         // overlay: q dead after sim GEMM

  const int NSPLIT = (ws_size >= 180453376ull) ? 4 : 3;

  wcvt_kernel<<<64, 256, 0, stream>>>(Wq, Wk, Wv, wq_bf, wk_bf, wv_bf);
  proj2_kernel<<<dim3(144, 16, 3), 256, 0, stream>>>(f_in, e_in, wq_bf, wk_bf, wv_bf, q, kmat, vt);
  if (NSPLIT == 4)
    gemm4<0, 0><<<1024, 256, 0, stream>>>(q, kmat, HW, NROW, 36, 2304, 4194304LL, sim, nullptr);
  else
    gemm4<2, 0><<<768, 256, 0, stream>>>(q, kmat, HW, NROW, 48, 3072, 4194304LL, sim, nullptr);
  softmaxN_kernel<<<2048, 256, 0, stream>>>(sim, P, NSPLIT);
  gemm4<1, 1><<<1152, 256, 0, stream>>>(P, vt, NROW, HW, 32, 0, 0LL, out, f_in);
}